// Round 15
// baseline (90.280 us; speedup 1.0000x reference)
//
#include <hip/hip_runtime.h>
#include <hip/hip_bf16.h>
#include <cstddef>

#define NE 65536
#define ND 256
#define NP 8
#define EB2 128               // consecutive edges per main block
#define NBK (NE / EB2)        // 512 main blocks

typedef short bf16x8 __attribute__((ext_vector_type(8)));
typedef float f32x4  __attribute__((ext_vector_type(4)));

__device__ __forceinline__ unsigned short f2bf(float f) {
  unsigned int u = __float_as_uint(f);
  u += 0x7FFFu + ((u >> 16) & 1u);   // round-to-nearest-even
  return (unsigned short)(u >> 16);
}
__device__ __forceinline__ float bf2f(unsigned short h) {
  return __uint_as_float(((unsigned int)h) << 16);
}
__device__ __forceinline__ int load_idx(const void* idxraw, int is32, int e) {
  return is32 ? ((const int*)idxraw)[e] : (int)((const long long*)idxraw)[e];
}

// ---- k_prep: W_bil -> B-frag bf16 layout; v_p = b_lr[p] @ W_bil (fp32) ----
__global__ __launch_bounds__(256) void k_prep(const float* __restrict__ Wbil,
                                              const float* __restrict__ blr,
                                              unsigned short* __restrict__ WbT,
                                              float* __restrict__ v) {
  int b = blockIdx.x, t = threadIdx.x;
  if (b < 32) {
    int s = b * 256 + t;
    int kt = s >> 10, c = (s >> 6) & 15, l = s & 63;
    int col = c * 16 + (l & 15);
    int k0 = kt * 32 + (l >> 4) * 8;
    union { uint4 u; unsigned short h[8]; } uu;
#pragma unroll
    for (int j = 0; j < 8; ++j)
      uu.h[j] = f2bf(Wbil[(k0 + j) * ND + col]);
    *(uint4*)(WbT + (size_t)s * 8) = uu.u;
  } else {
    int p = b - 32;
    float s = 0.f;
    for (int k = 0; k < ND; ++k)
      s = fmaf(blr[p * ND + k], Wbil[k * ND + t], s);
    v[p * ND + t] = s;
  }
}

// ---- k_cpre: C_p = W_lr[p]^T @ W_bil (bf16 MFMA), B-frag layout ----
__global__ __launch_bounds__(256) void k_cpre(const float* __restrict__ Wlr,
                                              const unsigned short* __restrict__ WbT,
                                              unsigned short* __restrict__ Cst) {
  __shared__ unsigned short aF[2048 * 8];
  int blk = blockIdx.x;
  int p = blk >> 2;
  int i0 = (blk & 3) * 64;
  int tid = threadIdx.x;
  const float* Wp = Wlr + (size_t)p * ND * ND;
#pragma unroll
  for (int it = 0; it < 8; ++it) {
    int s = tid + it * 256;
    int kt = s >> 8, r = (s >> 6) & 3, l = s & 63;
    int i = r * 16 + (l & 15);
    int k0 = kt * 32 + (l >> 4) * 8;
    union { uint4 u; unsigned short h[8]; } uu;
#pragma unroll
    for (int j = 0; j < 8; ++j)
      uu.h[j] = f2bf(Wp[(size_t)(k0 + j) * ND + i0 + i]);
    *(uint4*)(aF + (size_t)s * 8) = uu.u;
  }
  __syncthreads();
  int w = tid >> 6, l = tid & 63;
  f32x4 zero = {0.f, 0.f, 0.f, 0.f};
  f32x4 acc[16];
#pragma unroll
  for (int c = 0; c < 16; ++c) acc[c] = zero;
  for (int kt = 0; kt < 8; ++kt) {
    bf16x8 a = *(const bf16x8*)(aF + (size_t)((kt * 4 + w) * 64 + l) * 8);
#pragma unroll
    for (int c = 0; c < 16; ++c) {
      bf16x8 bb = *(const bf16x8*)(WbT + (size_t)((kt * 16 + c) * 64 + l) * 8);
      acc[c] = __builtin_amdgcn_mfma_f32_16x16x32_bf16(a, bb, acc[c], 0, 0, 0);
    }
  }
  unsigned short* Cp = Cst + (size_t)p * ND * ND;
#pragma unroll
  for (int c = 0; c < 16; ++c) {
#pragma unroll
    for (int q = 0; q < 4; ++q) {
      int i = i0 + w * 16 + ((l >> 4) * 4) + q;
      int j = c * 16 + (l & 15);
      int pos = ((i >> 5) * 16 + (j >> 4)) * 512 + (((i >> 3) & 3) * 16 + (j & 15)) * 8 + (i & 7);
      Cp[pos] = f2bf(acc[c][q]);
    }
  }
}

// ---- k_main v15: 128 NATURAL consecutive edges per block. ----
// Reads are purely sequential (the only access order this machine serves at
// multi-TB/s; permuted-row order caps at ~1.1 TB/s — R3-R14). The expert
// permutation happens entirely in LDS: wave 0 builds exact ballot sort
// tables; staging ds_writes each row into its locally-sorted slot; the GEMM
// runs per-expert 16-row strips at arbitrary offsets (spill rows computed &
// discarded); B (C_p frags, 64 VGPR) loaded once per expert via a STATIC
// unrolled expert loop. No global CSR/perm/hist/scan kernels at all.
__global__ __launch_bounds__(512, 1) void k_main(const float* __restrict__ zsrc,
                                                 const float* __restrict__ zdst,
                                                 const void* __restrict__ idxraw,
                                                 const unsigned short* __restrict__ Cst,
                                                 const float* __restrict__ v,
                                                 const float* __restrict__ bbil,
                                                 float* __restrict__ out) {
  __shared__ unsigned short zs[32768];   // 64 KiB: [row][kt*64+hi*16] frag chunks, XOR swz
  __shared__ unsigned short zd[32768];   // 64 KiB: [row][col*2] row-major, XOR swz
  __shared__ float red[8][EB2];          // 4 KiB
  __shared__ int sslot[EB2];             // natural row -> sorted slot
  __shared__ int lsrc[EB2];              // sorted slot -> natural row
  __shared__ int estart[NP + 1];
  int tid = threadIdx.x;
  int base = (int)blockIdx.x * EB2;
  int w = tid >> 6, l = tid & 63;

  // ---- wave 0: dtype sniff + exact ballot sort tables ----
  if (w == 0) {
    const unsigned int* wd = (const unsigned int*)idxraw;
    unsigned int vodd = wd[(base + l) * 2 + 1];   // high word if int64, else an idx value
    int is32 = __any(vodd != 0);                  // P(false|int32) = (1/8)^64 ~ 0
    int p0 = load_idx(idxraw, is32, base + l);
    int p1 = load_idx(idxraw, is32, base + 64 + l);
    unsigned long long lt = (l == 63) ? 0x7FFFFFFFFFFFFFFFull : ((1ull << l) - 1ull);
    int start = 0, s0 = 0, s1 = 0;
#pragma unroll
    for (int q = 0; q < NP; ++q) {
      unsigned long long m0 = __ballot(p0 == q);
      unsigned long long m1 = __ballot(p1 == q);
      if (l == q) estart[q] = start;              // exclusive prefix
      if (p0 == q) s0 = start + __popcll(m0 & lt);
      if (p1 == q) s1 = start + __popcll(m0) + __popcll(m1 & lt);
      start += __popcll(m0) + __popcll(m1);
    }
    if (l == 0) estart[NP] = EB2;
    sslot[l] = s0;       lsrc[s0] = l;
    sslot[64 + l] = s1;  lsrc[s1] = 64 + l;
  }
  __syncthreads();

  // ---- staging: wave w owns natural rows [w*16, w*16+16); lane l cols [4l,4l+4)
  // Sequential global reads; sorted LDS writes (8B each, swizzled).
  unsigned inrow_s = (unsigned)((l >> 3) * 64 + ((l & 7) >> 1) * 16 + (l & 1) * 8);
  unsigned inrow_d = (unsigned)(l * 8);
#pragma unroll
  for (int c4 = 0; c4 < 4; ++c4) {
    float4 fs[4], fd[4];
#pragma unroll
    for (int i = 0; i < 4; ++i) {
      int j = w * 16 + c4 * 4 + i;
      fs[i] = *(const float4*)(zsrc + (size_t)(base + j) * ND + l * 4);
      fd[i] = *(const float4*)(zdst + (size_t)(base + j) * ND + l * 4);
    }
#pragma unroll
    for (int i = 0; i < 4; ++i) {
      int j = w * 16 + c4 * 4 + i;
      int dr = sslot[j];
      unsigned sw = ((unsigned)dr & 7u) << 4;
      union { unsigned long long u; unsigned short h[4]; } us, ud;
      us.h[0] = f2bf(fs[i].x); us.h[1] = f2bf(fs[i].y);
      us.h[2] = f2bf(fs[i].z); us.h[3] = f2bf(fs[i].w);
      ud.h[0] = f2bf(fd[i].x); ud.h[1] = f2bf(fd[i].y);
      ud.h[2] = f2bf(fd[i].z); ud.h[3] = f2bf(fd[i].w);
      *(unsigned long long*)((char*)zs + (unsigned)dr * 512 + (inrow_s ^ sw)) = us.u;
      *(unsigned long long*)((char*)zd + (unsigned)dr * 512 + (inrow_d ^ sw)) = ud.u;
    }
  }
  __syncthreads();

  // ---- per-expert strip GEMM + fused epilogue; wave w owns 32 cols ----
  float bb0 = bbil[0];
  f32x4 zero = {0.f, 0.f, 0.f, 0.f};
#pragma unroll
  for (int p = 0; p < NP; ++p) {
    int rs = estart[p], re_ = estart[p + 1];
    int nst = (re_ - rs + 15) >> 4;
    if (nst <= 0) continue;
    const unsigned short* Cp = Cst + (size_t)p * ND * ND;
    bf16x8 bfr[2][8];
    float vloc[2];
#pragma unroll
    for (int cl = 0; cl < 2; ++cl) {
#pragma unroll
      for (int kt = 0; kt < 8; ++kt)
        bfr[cl][kt] = *(const bf16x8*)(Cp + (size_t)((kt * 16 + (w * 2 + cl)) * 64 + l) * 8);
      vloc[cl] = v[p * ND + (w * 2 + cl) * 16 + (l & 15)];
    }
    for (int s = 0; s < nst; ++s) {
      int r0 = rs + s * 16;
      int dr = r0 + (l & 15); if (dr > EB2 - 1) dr = EB2 - 1;   // spill rows: clamp, discard
      int hi = l >> 4;
      f32x4 acc0 = zero, acc1 = zero;
#pragma unroll
      for (int kt = 0; kt < 8; ++kt) {
        unsigned ba = (unsigned)dr * 512 +
                      (((unsigned)(kt * 64 + hi * 16)) ^ (((unsigned)dr & 7u) << 4));
        bf16x8 a = *(const bf16x8*)((const char*)zs + ba);
        acc0 = __builtin_amdgcn_mfma_f32_16x16x32_bf16(a, bfr[0][kt], acc0, 0, 0, 0);
        acc1 = __builtin_amdgcn_mfma_f32_16x16x32_bf16(a, bfr[1][kt], acc1, 0, 0, 0);
      }
#pragma unroll
      for (int q = 0; q < 4; ++q) {
        int row = r0 + (l >> 4) * 4 + q;       // D-layout: col=l&15, row=(l>>4)*4+reg
        int rc = row > EB2 - 1 ? EB2 - 1 : row;
        unsigned sw = ((unsigned)rc & 7u) << 4;
        int col0 = (w * 2 + 0) * 16 + (l & 15);
        int col1 = col0 + 16;
        unsigned b0 = (unsigned)rc * 512 + (((unsigned)(col0 * 2)) ^ sw);
        unsigned b1 = (unsigned)rc * 512 + (((unsigned)(col1 * 2)) ^ sw);
        float sv = fmaf(acc0[q] + vloc[0],
                        bf2f(*(const unsigned short*)((const char*)zd + b0)), 0.f);
        sv = fmaf(acc1[q] + vloc[1],
                  bf2f(*(const unsigned short*)((const char*)zd + b1)), sv);
        sv += __shfl_xor(sv, 1, 64);
        sv += __shfl_xor(sv, 2, 64);
        sv += __shfl_xor(sv, 4, 64);
        sv += __shfl_xor(sv, 8, 64);
        if ((l & 15) == 0 && row < re_) red[w][row] = sv;
      }
    }
  }
  __syncthreads();
  if (tid < EB2) {
    float sc = bb0;
#pragma unroll
    for (int ww = 0; ww < 8; ++ww) sc += red[ww][tid];
    out[base + lsrc[tid]] = sc;
  }
}

extern "C" void kernel_launch(void* const* d_in, const int* in_sizes, int n_in,
                              void* d_out, int out_size, void* d_ws, size_t ws_size,
                              hipStream_t stream) {
  // setup_inputs() dict order: z_src, z_dst, W_lr, b_lr, W_bil, b_bil, lr_pair_idx
  const float* zsrc = (const float*)d_in[0];
  const float* zdst = (const float*)d_in[1];
  const float* Wlr  = (const float*)d_in[2];
  const float* blr  = (const float*)d_in[3];
  const float* Wbil = (const float*)d_in[4];
  const float* bbil = (const float*)d_in[5];
  const void*  idx  = (const void*)d_in[6];
  float* out = (float*)d_out;

  char* ws = (char*)d_ws;
  unsigned short* WbT = (unsigned short*)(ws + 4096);              // 128 KiB
  float* v            = (float*)(ws + 4096 + 131072);              // 8 KiB
  unsigned short* Cst = (unsigned short*)(ws + 4096 + 131072 + 8192); // 1 MiB

  k_prep<<<40, 256, 0, stream>>>(Wbil, blr, WbT, v);
  k_cpre<<<32, 256, 0, stream>>>(Wlr, WbT, Cst);
  k_main<<<NBK, 512, 0, stream>>>(zsrc, zdst, idx, Cst, v, bbil, out);
}